// Round 9
// baseline (186.722 us; speedup 1.0000x reference)
//
#include <hip/hip_runtime.h>
#include <hip/hip_bf16.h>
#include <cstdint>
#include <cstddef>

typedef __bf16 bf16;
typedef __attribute__((ext_vector_type(8))) __bf16 bf16x8;
typedef __attribute__((ext_vector_type(16))) float f32x16;

static_assert(sizeof(bf16x8) == 16, "bf16x8 must be 16B");

#define NTASK 34
#define BTOT 16384
#define WSTRIDE 73728   // bf16 elems per task stream: 140KB real + 4KB pad = 144KB

__device__ __forceinline__ f32x16 mfma32(bf16x8 a, bf16x8 b, f32x16 c) {
  return __builtin_amdgcn_mfma_f32_32x32x16_bf16(a, b, c, 0, 0, 0);
}

__device__ __forceinline__ void gload_lds16(const void* g, void* l) {
  __builtin_amdgcn_global_load_lds((__attribute__((address_space(1))) void*)g,
                                   (__attribute__((address_space(3))) void*)l,
                                   16, 0, 0);
}

__device__ __forceinline__ unsigned pack2(float lo, float hi) {
  union { __bf16 h[2]; unsigned u; } v;
  v.h[0] = (__bf16)lo; v.h[1] = (__bf16)hi;
  return v.u;
}

// vdst hi-lanes <-> vsrc lo-lanes exchange (both modified)
__device__ __forceinline__ void pl32swap(unsigned &a, unsigned &b) {
  asm volatile("v_permlane32_swap_b32 %0, %1" : "+v"(a), "+v"(b));
}

// ---------------- prep (merged) ----------------
// blocks [0,1190): weights -> 32x32 A-frag blocks (1KB), per-task stream.
//   W1: blocks mt*17+ks (ks=16 bias row); W2: 68+mt*9+ks; W3: 104+mt*9+ks.
// blocks [1190,3238): state -> 32x32 B-frag blocks.
__global__ void prep_all(const float* __restrict__ W1, const float* __restrict__ W2,
                         const float* __restrict__ W3, const float* __restrict__ b1,
                         const float* __restrict__ b2, const float* __restrict__ b3,
                         const float* __restrict__ state,
                         bf16* __restrict__ wdst, bf16* __restrict__ sdst) {
  int bid = blockIdx.x;
  if (bid < 1190) {
    int idx = bid * 256 + threadIdx.x;    // 34*140*64 = 304640
    if (idx >= 304640) return;
    int n = idx / (140 * 64);
    int r = idx - n * (140 * 64);
    int bb = r >> 6, l = r & 63;
    const float *W, *bias; int real, mt, ks, Kt;
    if (bb < 68)       { W = W1; bias = b1; mt = bb / 17; ks = bb - mt * 17; real = 16; Kt = 256; }
    else if (bb < 104) { W = W2; bias = b2; int t = bb - 68;  mt = t / 9; ks = t - mt * 9; real = 8; Kt = 128; }
    else               { W = W3; bias = b3; int t = bb - 104; mt = t / 9; ks = t - mt * 9; real = 8; Kt = 128; }
    int col = mt * 32 + (l & 31);
    bf16x8 v;
    if (ks < real) {
      int k0 = ks * 16 + ((l >> 5) << 3);
      const float* s = W + ((size_t)n * Kt + k0) * 128 + col;
#pragma unroll
      for (int j = 0; j < 8; ++j) v[j] = (bf16)s[(size_t)j * 128];
    } else {
#pragma unroll
      for (int j = 0; j < 8; ++j) v[j] = (bf16)0.f;
      if (l < 32) v[0] = (bf16)bias[n * 128 + col];
    }
    *(bf16x8*)(wdst + (size_t)n * WSTRIDE + bb * 512 + l * 8) = v;
  } else {
    int idx = (bid - 1190) * 256 + threadIdx.x;   // 524288 exact
    int rb = idx >> 10;
    int r = idx & 1023;
    int ks = r >> 6;
    int l = r & 63;
    int b = rb * 32 + (l & 31);
    int k0 = ks * 16 + ((l >> 5) << 3);
    const float* s = state + (size_t)b * 256 + k0;
    bf16x8 v;
#pragma unroll
    for (int j = 0; j < 8; ++j) v[j] = (bf16)s[j];
    *(bf16x8*)(sdst + (size_t)(rb * 16 + ks) * 512 + l * 8) = v;
  }
}

__global__ void prep_langn(const float* __restrict__ lang, float* __restrict__ out) {
  __shared__ float red[2];
  int n = blockIdx.x;
  int t = threadIdx.x;                        // 128 threads
  float v = lang[(size_t)n * 128 + t];
  float ss = v * v;
#pragma unroll
  for (int m = 1; m < 64; m <<= 1) ss += __shfl_xor(ss, m);
  if ((t & 63) == 0) red[t >> 6] = ss;
  __syncthreads();
  float s = red[0] + red[1];
  float sc = 1.0f / fmaxf(sqrtf(s), 1e-8f);
  out[(size_t)n * 128 + t] = v * sc;
}

// ---------------- pass 1 ----------------
// 256 thr = 4 waves, 64 rows/wave; 72KB LDS => 2 independent blocks/CU.
// Two-phase staging: W1 (68KB) -> GEMM1 -> restage W2/W3 (72KB) -> GEMM2/3.
// Swapped 32x32x16 MFMA, K-augmented bias, permlane register transitions.
// q stored directly, [n][row][128] layout.

__global__ void __launch_bounds__(256, 2)
pass1_kernel(const int* __restrict__ task_id, const bf16* __restrict__ wstream,
             const bf16* __restrict__ sf, const float* __restrict__ langn,
             float* __restrict__ cs_t, float* __restrict__ inv_t,
             bf16* __restrict__ q_t) {
  __shared__ __align__(16) bf16 shW[36864];   // 72KB: W1 phase, then W2/W3

  const int tid = threadIdx.x;
  const int l = tid & 63;
  const int w = tid >> 6;          // wave 0..3
  const int hi = l >> 5;
  const int b = l & 31;
  const int n = blockIdx.x >> 6;   // task
  const int rg = blockIdx.x & 63;  // 256-row group
  const int rowbase = rg * 256 + w * 64;
  const int row0 = rowbase + b;    // tile0 row (tile1 = +32)
  const int rb0 = rg * 8 + w * 2;  // frag-block index tile0

  // ---- stage A: W1+bias (68KB) -> LDS[0,68KB)
  const bf16* wbase = wstream + (size_t)n * WSTRIDE;
#pragma unroll
  for (int c = 0; c < 17; ++c)
    gload_lds16(wbase + c * 2048 + tid * 8, shW + c * 2048 + tid * 8);

  // B-frag rolling buffers + row meta (issued AFTER stages: vmcnt(10) = stages done)
  const bf16* sb0 = sf + (size_t)rb0 * 8192 + l * 8;
  const bf16* sb1 = sb0 + 8192;
  bf16x8 s0[4], s1[4];
#pragma unroll
  for (int i = 0; i < 4; ++i) {
    s0[i] = *(const bf16x8*)(sb0 + i * 512);
    s1[i] = *(const bf16x8*)(sb1 + i * 512);
  }
  int tidn0 = task_id[row0];
  int tidn1 = task_id[row0 + 32];

  // const "1" B-frag for the bias K-augment step
  union { unsigned u[4]; bf16x8 v; } cf;
  cf.u[0] = (l < 32) ? 0x3f80u : 0u;
  cf.u[1] = 0u; cf.u[2] = 0u; cf.u[3] = 0u;

  asm volatile("s_waitcnt vmcnt(10)" ::: "memory");
  __builtin_amdgcn_s_barrier();

  f32x16 z;
#pragma unroll
  for (int i = 0; i < 16; ++i) z[i] = 0.f;
  f32x16 acc0[4] = {z, z, z, z};
  f32x16 acc1[4] = {z, z, z, z};

  // ---- GEMM1: 16 data ksteps + const kstep
#pragma unroll
  for (int ks = 0; ks < 16; ++ks) {
    bf16x8 sv0 = s0[ks & 3], sv1 = s1[ks & 3];
    if (ks < 12) {
      s0[ks & 3] = *(const bf16x8*)(sb0 + (ks + 4) * 512);
      s1[ks & 3] = *(const bf16x8*)(sb1 + (ks + 4) * 512);
    }
    __builtin_amdgcn_s_setprio(1);
#pragma unroll
    for (int mt = 0; mt < 4; ++mt) {
      bf16x8 wf = *(const bf16x8*)(shW + ((mt * 17 + ks) << 9) + l * 8);
      acc0[mt] = mfma32(wf, sv0, acc0[mt]);
      acc1[mt] = mfma32(wf, sv1, acc1[mt]);
    }
    __builtin_amdgcn_s_setprio(0);
  }
#pragma unroll
  for (int mt = 0; mt < 4; ++mt) {
    bf16x8 wf = *(const bf16x8*)(shW + ((mt * 17 + 16) << 9) + l * 8);
    acc0[mt] = mfma32(wf, cf.v, acc0[mt]);
    acc1[mt] = mfma32(wf, cf.v, acc1[mt]);
  }

  __syncthreads();   // all waves done reading W1 region

  // ---- stage B: W2/W3 (72KB) -> LDS[0,72KB), overwrites W1
#pragma unroll
  for (int c = 0; c < 18; ++c)
    gload_lds16(wbase + 34816 + c * 2048 + tid * 8, shW + c * 2048 + tid * 8);

  // ---- transition 1 (VALU runs under stage-B flight)
  auto transition = [&](f32x16* acc, bf16x8* f) {
#pragma unroll
    for (int mt = 0; mt < 4; ++mt) {
      unsigned p[8];
#pragma unroll
      for (int q = 0; q < 4; ++q) {
        p[2 * q]     = pack2(fmaxf(acc[mt][4 * q + 0], 0.f), fmaxf(acc[mt][4 * q + 1], 0.f));
        p[2 * q + 1] = pack2(fmaxf(acc[mt][4 * q + 2], 0.f), fmaxf(acc[mt][4 * q + 3], 0.f));
      }
      pl32swap(p[0], p[2]); pl32swap(p[1], p[3]);
      pl32swap(p[4], p[6]); pl32swap(p[5], p[7]);
      union { unsigned u[4]; bf16x8 v; } e, o;
      e.u[0] = p[0]; e.u[1] = p[1]; e.u[2] = p[2]; e.u[3] = p[3];
      o.u[0] = p[4]; o.u[1] = p[5]; o.u[2] = p[6]; o.u[3] = p[7];
      f[2 * mt] = e.v; f[2 * mt + 1] = o.v;
    }
  };

  bf16x8 f2a[8], f2b[8];
  transition(acc0, f2a);
  transition(acc1, f2b);

  asm volatile("s_waitcnt vmcnt(0)" ::: "memory");
  __builtin_amdgcn_s_barrier();

  // ---- GEMM2: 8 data ksteps + const (W2 at LDS offset 0)
#pragma unroll
  for (int mt = 0; mt < 4; ++mt) { acc0[mt] = z; acc1[mt] = z; }
#pragma unroll
  for (int ks = 0; ks < 8; ++ks) {
    __builtin_amdgcn_s_setprio(1);
#pragma unroll
    for (int mt = 0; mt < 4; ++mt) {
      bf16x8 wf = *(const bf16x8*)(shW + ((mt * 9 + ks) << 9) + l * 8);
      acc0[mt] = mfma32(wf, f2a[ks], acc0[mt]);
      acc1[mt] = mfma32(wf, f2b[ks], acc1[mt]);
    }
    __builtin_amdgcn_s_setprio(0);
  }
#pragma unroll
  for (int mt = 0; mt < 4; ++mt) {
    bf16x8 wf = *(const bf16x8*)(shW + ((mt * 9 + 8) << 9) + l * 8);
    acc0[mt] = mfma32(wf, cf.v, acc0[mt]);
    acc1[mt] = mfma32(wf, cf.v, acc1[mt]);
  }

  bf16x8 f3a[8], f3b[8];
  transition(acc0, f3a);
  transition(acc1, f3b);

  // ---- GEMM3: 8 data ksteps + const (W3 at LDS offset 36KB)
#pragma unroll
  for (int mt = 0; mt < 4; ++mt) { acc0[mt] = z; acc1[mt] = z; }
#pragma unroll
  for (int ks = 0; ks < 8; ++ks) {
    __builtin_amdgcn_s_setprio(1);
#pragma unroll
    for (int mt = 0; mt < 4; ++mt) {
      bf16x8 wf = *(const bf16x8*)(shW + ((36 + mt * 9 + ks) << 9) + l * 8);
      acc0[mt] = mfma32(wf, f3a[ks], acc0[mt]);
      acc1[mt] = mfma32(wf, f3b[ks], acc1[mt]);
    }
    __builtin_amdgcn_s_setprio(0);
  }
#pragma unroll
  for (int mt = 0; mt < 4; ++mt) {
    bf16x8 wf = *(const bf16x8*)(shW + ((36 + mt * 9 + 8) << 9) + l * 8);
    acc0[mt] = mfma32(wf, cf.v, acc0[mt]);
    acc1[mt] = mfma32(wf, cf.v, acc1[mt]);
  }

  // ---- epilogue: ssq/dot (lane holds 64 of 128 cols of ONE row; partner l^32 rest)
  float ssq0 = 0.f, dot0 = 0.f, ssq1 = 0.f, dot1 = 0.f;
  const float* lg0b = langn + (size_t)tidn0 * 128;
  const float* lg1b = langn + (size_t)tidn1 * 128;
#pragma unroll
  for (int mt = 0; mt < 4; ++mt)
#pragma unroll
    for (int q = 0; q < 4; ++q) {
      int c0 = mt * 32 + q * 8 + 4 * hi;
      float4 lg0 = *(const float4*)(lg0b + c0);
      float4 lg1 = *(const float4*)(lg1b + c0);
      float a0 = acc0[mt][4 * q + 0], a1 = acc0[mt][4 * q + 1];
      float a2 = acc0[mt][4 * q + 2], a3 = acc0[mt][4 * q + 3];
      ssq0 += a0 * a0 + a1 * a1 + a2 * a2 + a3 * a3;
      dot0 += a0 * lg0.x + a1 * lg0.y + a2 * lg0.z + a3 * lg0.w;
      float b0 = acc1[mt][4 * q + 0], b1v = acc1[mt][4 * q + 1];
      float b2v = acc1[mt][4 * q + 2], b3v = acc1[mt][4 * q + 3];
      ssq1 += b0 * b0 + b1v * b1v + b2v * b2v + b3v * b3v;
      dot1 += b0 * lg1.x + b1v * lg1.y + b2v * lg1.z + b3v * lg1.w;
    }
  ssq0 += __shfl_xor(ssq0, 32); dot0 += __shfl_xor(dot0, 32);
  ssq1 += __shfl_xor(ssq1, 32); dot1 += __shfl_xor(dot1, 32);
  if (l < 32) {
    float inv0 = rsqrtf(ssq0), inv1 = rsqrtf(ssq1);
    cs_t[(size_t)row0 * NTASK + n] = dot0 * inv0;
    inv_t[(size_t)row0 * NTASK + n] = inv0;
    cs_t[(size_t)(row0 + 32) * NTASK + n] = dot1 * inv1;
    inv_t[(size_t)(row0 + 32) * NTASK + n] = inv1;
  }

  // ---- q store: direct uint2, [n][row][128] layout (L2 merges 8B granules)
  bf16* q0 = q_t + ((size_t)n * BTOT + row0) * 128;
  bf16* q1 = q0 + (size_t)32 * 128;
#pragma unroll
  for (int mt = 0; mt < 4; ++mt)
#pragma unroll
    for (int qq = 0; qq < 4; ++qq) {
      int cb = mt * 32 + qq * 8 + 4 * hi;
      uint2 p0, p1;
      p0.x = pack2(acc0[mt][4 * qq + 0], acc0[mt][4 * qq + 1]);
      p0.y = pack2(acc0[mt][4 * qq + 2], acc0[mt][4 * qq + 3]);
      p1.x = pack2(acc1[mt][4 * qq + 0], acc1[mt][4 * qq + 1]);
      p1.y = pack2(acc1[mt][4 * qq + 2], acc1[mt][4 * qq + 3]);
      *(uint2*)(q0 + cb) = p0;
      *(uint2*)(q1 + cb) = p1;
    }
}

// ---------------- pass 3: per-row combine (1 wave per row) ----------------

__global__ void __launch_bounds__(256)
pass3_kernel(const float* __restrict__ state, const int* __restrict__ task_id,
             const float* __restrict__ prior, const float* __restrict__ cs_t,
             const float* __restrict__ inv_t, const bf16* __restrict__ q_t,
             float* __restrict__ out_rep, float* __restrict__ out_ltp,
             float* __restrict__ out_tgt, float* __restrict__ out_lat) {
  __shared__ float sppiv[4][NTASK];
  int w = threadIdx.x >> 6, l = threadIdx.x & 63;
  size_t row = (size_t)blockIdx.x * 4 + w;

  // softmax(prior) * inv (inv folded so latent uses unnormalized q)
  float pv = (l < NTASK) ? prior[row * NTASK + l] : -INFINITY;
  float iv = (l < NTASK) ? inv_t[row * NTASK + l] : 0.0f;
  float m = pv;
#pragma unroll
  for (int mm = 1; mm < 64; mm <<= 1) m = fmaxf(m, __shfl_xor(m, mm));
  float e = (l < NTASK) ? expf(pv - m) : 0.0f;
  float s = e;
#pragma unroll
  for (int mm = 1; mm < 64; mm <<= 1) s += __shfl_xor(s, mm);
  if (l < NTASK) sppiv[w][l] = (e / s) * iv;

  // log_softmax(cos*10)
  float c = (l < NTASK) ? cs_t[row * NTASK + l] * 10.0f : -1e30f;
  float cm = c;
#pragma unroll
  for (int mm = 1; mm < 64; mm <<= 1) cm = fmaxf(cm, __shfl_xor(cm, mm));
  float ce = (l < NTASK) ? expf(c - cm) : 0.0f;
  float cs = ce;
#pragma unroll
  for (int mm = 1; mm < 64; mm <<= 1) cs += __shfl_xor(cs, mm);
  if (l < NTASK) out_ltp[row * NTASK + l] = c - cm - logf(cs);

  int tg = task_id[row];
  float ivt = __shfl(iv, tg);
  __syncthreads();

  // latent: lane covers cols {2l, 2l+1}; q_t [n][row][128] (coalesced per n)
  float lat0 = 0.f, lat1 = 0.f;
#pragma unroll
  for (int nn = 0; nn < NTASK; ++nn) {
    float pw = sppiv[w][nn];
    union { unsigned u; __bf16 h[2]; } q;
    q.u = *(const unsigned*)(q_t + ((size_t)nn * BTOT + row) * 128 + 2 * l);
    lat0 += pw * (float)q.h[0];
    lat1 += pw * (float)q.h[1];
  }
  float2 lv = {lat0, lat1};
  *(float2*)(out_lat + row * 128 + 2 * l) = lv;
  *(float2*)(out_rep + row * 384 + 256 + 2 * l) = lv;

  // latent_target = q[tg] * inv[tg]
  union { unsigned u; __bf16 h[2]; } qt;
  qt.u = *(const unsigned*)(q_t + ((size_t)tg * BTOT + row) * 128 + 2 * l);
  float2 tv = {(float)qt.h[0] * ivt, (float)qt.h[1] * ivt};
  *(float2*)(out_tgt + row * 128 + 2 * l) = tv;

  // state passthrough
  float4 sv = *(const float4*)(state + row * 256 + l * 4);
  *(float4*)(out_rep + row * 384 + l * 4) = sv;
}

// ---------------- launch ----------------

extern "C" void kernel_launch(void* const* d_in, const int* in_sizes, int n_in,
                              void* d_out, int out_size, void* d_ws, size_t ws_size,
                              hipStream_t stream) {
  (void)in_sizes; (void)n_in; (void)out_size; (void)ws_size;
  const float* state = (const float*)d_in[0];
  const int* task_id = (const int*)d_in[1];
  const float* prior = (const float*)d_in[2];
  const float* W1 = (const float*)d_in[3];
  const float* b1 = (const float*)d_in[4];
  const float* W2 = (const float*)d_in[5];
  const float* b2 = (const float*)d_in[6];
  const float* W3 = (const float*)d_in[7];
  const float* b3 = (const float*)d_in[8];
  const float* lang = (const float*)d_in[9];

  char* ws = (char*)d_ws;
  bf16* wstream = (bf16*)(ws + 0);           //   5,013,504 B (34 x 144KB)
  bf16* sf      = (bf16*)(ws + 5013504);     //   8,388,608 B
  float* langn  = (float*)(ws + 13402112);   //      17,408 B
  float* cs_t   = (float*)(ws + 13419520);   //   2,228,224 B [16384][34]
  float* inv_t  = (float*)(ws + 15647744);   //   2,228,224 B [16384][34]
  bf16* q_t     = (bf16*)(ws + 17875968);    // 142,606,336 B [34][16384][128]
                                             // total 160,482,304 B

  float* out = (float*)d_out;
  float* out_rep = out;                 // [B,384]
  float* out_ltp = out + 6291456;       // [B,34]
  float* out_tgt = out + 6848512;       // [B,128]
  float* out_lat = out + 8945664;       // [B,128]

  prep_all<<<3238, 256, 0, stream>>>(W1, W2, W3, b1, b2, b3, state, wstream, sf);
  prep_langn<<<NTASK, 128, 0, stream>>>(lang, langn);
  pass1_kernel<<<NTASK * 64, 256, 0, stream>>>(task_id, wstream, sf, langn,
                                               cs_t, inv_t, q_t);
  pass3_kernel<<<4096, 256, 0, stream>>>(state, task_id, prior, cs_t, inv_t, q_t,
                                         out_rep, out_ltp, out_tgt, out_lat);
}

// Round 10
// 173.809 us; speedup vs baseline: 1.0743x; 1.0743x over previous
//
#include <hip/hip_runtime.h>
#include <hip/hip_bf16.h>
#include <cstdint>
#include <cstddef>

typedef __bf16 bf16;
typedef __attribute__((ext_vector_type(8))) __bf16 bf16x8;
typedef __attribute__((ext_vector_type(16))) float f32x16;

static_assert(sizeof(bf16x8) == 16, "bf16x8 must be 16B");

#define NTASK 34
#define BTOT 16384
#define WSTRIDE 73728   // bf16 elems per task stream: 140KB real + 4KB pad

__device__ __forceinline__ f32x16 mfma32(bf16x8 a, bf16x8 b, f32x16 c) {
  return __builtin_amdgcn_mfma_f32_32x32x16_bf16(a, b, c, 0, 0, 0);
}

__device__ __forceinline__ void gload_lds16(const void* g, void* l) {
  __builtin_amdgcn_global_load_lds((__attribute__((address_space(1))) void*)g,
                                   (__attribute__((address_space(3))) void*)l,
                                   16, 0, 0);
}

__device__ __forceinline__ unsigned pack2(float lo, float hi) {
  union { __bf16 h[2]; unsigned u; } v;
  v.h[0] = (__bf16)lo; v.h[1] = (__bf16)hi;
  return v.u;
}

__device__ __forceinline__ void pl32swap(unsigned &a, unsigned &b) {
  asm volatile("v_permlane32_swap_b32 %0, %1" : "+v"(a), "+v"(b));
}

// ---------------- prep (merged) ----------------
// blocks [0,1190): weights -> 32x32 A-frag blocks (1KB), per-task stream.
//   W1: blocks mt*17+ks (ks=16 bias row); W2: 68+mt*9+ks; W3: 104+mt*9+ks.
// blocks [1190,3238): state -> 32x32 B-frag blocks.
__global__ void prep_all(const float* __restrict__ W1, const float* __restrict__ W2,
                         const float* __restrict__ W3, const float* __restrict__ b1,
                         const float* __restrict__ b2, const float* __restrict__ b3,
                         const float* __restrict__ state,
                         bf16* __restrict__ wdst, bf16* __restrict__ sdst) {
  int bid = blockIdx.x;
  if (bid < 1190) {
    int idx = bid * 256 + threadIdx.x;    // 34*140*64 = 304640
    if (idx >= 304640) return;
    int n = idx / (140 * 64);
    int r = idx - n * (140 * 64);
    int bb = r >> 6, l = r & 63;
    const float *W, *bias; int real, mt, ks, Kt;
    if (bb < 68)       { W = W1; bias = b1; mt = bb / 17; ks = bb - mt * 17; real = 16; Kt = 256; }
    else if (bb < 104) { W = W2; bias = b2; int t = bb - 68;  mt = t / 9; ks = t - mt * 9; real = 8; Kt = 128; }
    else               { W = W3; bias = b3; int t = bb - 104; mt = t / 9; ks = t - mt * 9; real = 8; Kt = 128; }
    int col = mt * 32 + (l & 31);
    bf16x8 v;
    if (ks < real) {
      int k0 = ks * 16 + ((l >> 5) << 3);
      const float* s = W + ((size_t)n * Kt + k0) * 128 + col;
#pragma unroll
      for (int j = 0; j < 8; ++j) v[j] = (bf16)s[(size_t)j * 128];
    } else {
#pragma unroll
      for (int j = 0; j < 8; ++j) v[j] = (bf16)0.f;
      if (l < 32) v[0] = (bf16)bias[n * 128 + col];
    }
    *(bf16x8*)(wdst + (size_t)n * WSTRIDE + bb * 512 + l * 8) = v;
  } else {
    int idx = (bid - 1190) * 256 + threadIdx.x;   // 524288 exact
    int rb = idx >> 10;
    int r = idx & 1023;
    int ks = r >> 6;
    int l = r & 63;
    int b = rb * 32 + (l & 31);
    int k0 = ks * 16 + ((l >> 5) << 3);
    const float* s = state + (size_t)b * 256 + k0;
    bf16x8 v;
#pragma unroll
    for (int j = 0; j < 8; ++j) v[j] = (bf16)s[j];
    *(bf16x8*)(sdst + (size_t)(rb * 16 + ks) * 512 + l * 8) = v;
  }
}

__global__ void prep_langn(const float* __restrict__ lang, float* __restrict__ out) {
  __shared__ float red[2];
  int n = blockIdx.x;
  int t = threadIdx.x;                        // 128 threads
  float v = lang[(size_t)n * 128 + t];
  float ss = v * v;
#pragma unroll
  for (int m = 1; m < 64; m <<= 1) ss += __shfl_xor(ss, m);
  if ((t & 63) == 0) red[t >> 6] = ss;
  __syncthreads();
  float s = red[0] + red[1];
  float sc = 1.0f / fmaxf(sqrtf(s), 1e-8f);
  out[(size_t)n * 128 + t] = v * sc;
}

// softmax(prior) -> f32 transposed pp_t[34][B]
__global__ void prep_pprior(const float* __restrict__ prior, float* __restrict__ ppt) {
  int row = blockIdx.x * 4 + (threadIdx.x >> 6);
  int lane = threadIdx.x & 63;
  float v = (lane < NTASK) ? prior[(size_t)row * NTASK + lane] : -INFINITY;
  float m = v;
#pragma unroll
  for (int mm = 1; mm < 64; mm <<= 1) m = fmaxf(m, __shfl_xor(m, mm));
  float e = (lane < NTASK) ? expf(v - m) : 0.0f;
  float s = e;
#pragma unroll
  for (int mm = 1; mm < 64; mm <<= 1) s += __shfl_xor(s, mm);
  if (lane < NTASK) ppt[(size_t)lane * BTOT + row] = e / s;
}

// ---------------- pass 1: task-fused, latent in registers ----------------
// grid = 256 blocks: bid = tg*64 + rg. Block = 4 waves x 64 rows = 256 rows,
// loops over its task group (tg<2 ? 9 : 8 tasks). 140KB LDS (A=W1, B=W2W3),
// cross-task pipelined staging. 1 block/CU, 1 wave/SIMD, 512-reg budget.
// q never materialized: latent accumulated in f32 registers across tasks.

__global__ void __launch_bounds__(256, 1)
pass1_kernel(const int* __restrict__ task_id, const bf16* __restrict__ wstream,
             const bf16* __restrict__ sf, const float* __restrict__ langn,
             const float* __restrict__ pp_t,
             float* __restrict__ cs_t, float* __restrict__ lat_part,
             float* __restrict__ out_tgt) {
  __shared__ __align__(16) bf16 shA[34816];   // 68KB: W1+bias frags
  __shared__ __align__(16) bf16 shB[36864];   // 72KB: W2+W3 frags

  const int tid = threadIdx.x;
  const int l = tid & 63;
  const int w = tid >> 6;          // wave 0..3
  const int hi = l >> 5;
  const int b = l & 31;
  const int tg = blockIdx.x >> 6;  // task group 0..3
  const int rg = blockIdx.x & 63;  // 256-row group
  const int start = tg * 9 - ((tg > 2) ? (tg - 2) : 0);  // 0,9,18,26
  const int cnt = 9 - (tg >> 1);                          // 9,9,8,8
  const int rowbase = rg * 256 + w * 64;
  const int row0 = rowbase + b;    // tile0 row (tile1 = +32)
  const int rb0 = rg * 8 + w * 2;  // 32-row frag-block index tile0

  int tidn0 = task_id[row0];
  int tidn1 = task_id[row0 + 32];

  // prologue: stage A(task start)
  {
    const bf16* wb0 = wstream + (size_t)start * WSTRIDE;
#pragma unroll
    for (int c = 0; c < 17; ++c)
      gload_lds16(wb0 + c * 2048 + tid * 8, shA + c * 2048 + tid * 8);
  }

  // const "1" B-frag for the bias K-augment step
  union { unsigned u[4]; bf16x8 v; } cf;
  cf.u[0] = (l < 32) ? 0x3f80u : 0u;
  cf.u[1] = 0u; cf.u[2] = 0u; cf.u[3] = 0u;

  f32x16 z;
#pragma unroll
  for (int i = 0; i < 16; ++i) z[i] = 0.f;
  f32x16 lat0[4] = {z, z, z, z};
  f32x16 lat1[4] = {z, z, z, z};

  const bf16* sb0 = sf + (size_t)rb0 * 8192 + l * 8;
  const bf16* sb1 = sb0 + 8192;

  auto transition = [&](f32x16* acc, bf16x8* f) {
#pragma unroll
    for (int mt = 0; mt < 4; ++mt) {
      unsigned p[8];
#pragma unroll
      for (int q = 0; q < 4; ++q) {
        p[2 * q]     = pack2(fmaxf(acc[mt][4 * q + 0], 0.f), fmaxf(acc[mt][4 * q + 1], 0.f));
        p[2 * q + 1] = pack2(fmaxf(acc[mt][4 * q + 2], 0.f), fmaxf(acc[mt][4 * q + 3], 0.f));
      }
      pl32swap(p[0], p[2]); pl32swap(p[1], p[3]);
      pl32swap(p[4], p[6]); pl32swap(p[5], p[7]);
      union { unsigned u[4]; bf16x8 v; } e, o;
      e.u[0] = p[0]; e.u[1] = p[1]; e.u[2] = p[2]; e.u[3] = p[3];
      o.u[0] = p[4]; o.u[1] = p[5]; o.u[2] = p[6]; o.u[3] = p[7];
      f[2 * mt] = e.v; f[2 * mt + 1] = o.v;
    }
  };

  for (int t = 0; t < cnt; ++t) {
    const int n = start + t;
    const bf16* wbase = wstream + (size_t)n * WSTRIDE;

    // stage B(n): W2/W3 (B free: last read in G3(t-1), fenced by end barrier)
#pragma unroll
    for (int c = 0; c < 18; ++c)
      gload_lds16(wbase + 34816 + c * 2048 + tid * 8, shB + c * 2048 + tid * 8);

    if (t == 0) {   // wait A(start): 18 B-ops younger than the 17 A-ops
      asm volatile("s_waitcnt vmcnt(18)" ::: "memory");
      __builtin_amdgcn_s_barrier();
    }

    f32x16 acc0[4] = {z, z, z, z};
    f32x16 acc1[4] = {z, z, z, z};

    // ---- GEMM1 from shA: 16 data ksteps + const kstep
    bf16x8 s0[4], s1[4];
#pragma unroll
    for (int i = 0; i < 4; ++i) {
      s0[i] = *(const bf16x8*)(sb0 + i * 512);
      s1[i] = *(const bf16x8*)(sb1 + i * 512);
    }
#pragma unroll
    for (int ks = 0; ks < 16; ++ks) {
      bf16x8 sv0 = s0[ks & 3], sv1 = s1[ks & 3];
      if (ks < 12) {
        s0[ks & 3] = *(const bf16x8*)(sb0 + (ks + 4) * 512);
        s1[ks & 3] = *(const bf16x8*)(sb1 + (ks + 4) * 512);
      }
      __builtin_amdgcn_s_setprio(1);
#pragma unroll
      for (int mt = 0; mt < 4; ++mt) {
        bf16x8 wf = *(const bf16x8*)(shA + ((mt * 17 + ks) << 9) + l * 8);
        acc0[mt] = mfma32(wf, sv0, acc0[mt]);
        acc1[mt] = mfma32(wf, sv1, acc1[mt]);
      }
      __builtin_amdgcn_s_setprio(0);
    }
#pragma unroll
    for (int mt = 0; mt < 4; ++mt) {
      bf16x8 wf = *(const bf16x8*)(shA + ((mt * 17 + 16) << 9) + l * 8);
      acc0[mt] = mfma32(wf, cf.v, acc0[mt]);
      acc1[mt] = mfma32(wf, cf.v, acc1[mt]);
    }

    bf16x8 f2a[8], f2b[8];
    transition(acc0, f2a);
    transition(acc1, f2b);

    asm volatile("s_waitcnt vmcnt(0)" ::: "memory");  // B(n) landed
    __builtin_amdgcn_s_barrier();                      // + WAR fence for A restage

    // ---- GEMM2 from shB; stage A(t+1) under it
    if (t + 1 < cnt) {
      const bf16* wnext = wstream + (size_t)(n + 1) * WSTRIDE;
#pragma unroll
      for (int c = 0; c < 17; ++c)
        gload_lds16(wnext + c * 2048 + tid * 8, shA + c * 2048 + tid * 8);
    }
#pragma unroll
    for (int mt = 0; mt < 4; ++mt) { acc0[mt] = z; acc1[mt] = z; }
#pragma unroll
    for (int ks = 0; ks < 8; ++ks) {
      __builtin_amdgcn_s_setprio(1);
#pragma unroll
      for (int mt = 0; mt < 4; ++mt) {
        bf16x8 wf = *(const bf16x8*)(shB + ((mt * 9 + ks) << 9) + l * 8);
        acc0[mt] = mfma32(wf, f2a[ks], acc0[mt]);
        acc1[mt] = mfma32(wf, f2b[ks], acc1[mt]);
      }
      __builtin_amdgcn_s_setprio(0);
    }
#pragma unroll
    for (int mt = 0; mt < 4; ++mt) {
      bf16x8 wf = *(const bf16x8*)(shB + ((mt * 9 + 8) << 9) + l * 8);
      acc0[mt] = mfma32(wf, cf.v, acc0[mt]);
      acc1[mt] = mfma32(wf, cf.v, acc1[mt]);
    }

    bf16x8 f3a[8], f3b[8];
    transition(acc0, f3a);
    transition(acc1, f3b);

    // ---- GEMM3 from shB
#pragma unroll
    for (int mt = 0; mt < 4; ++mt) { acc0[mt] = z; acc1[mt] = z; }
#pragma unroll
    for (int ks = 0; ks < 8; ++ks) {
      __builtin_amdgcn_s_setprio(1);
#pragma unroll
      for (int mt = 0; mt < 4; ++mt) {
        bf16x8 wf = *(const bf16x8*)(shB + ((36 + mt * 9 + ks) << 9) + l * 8);
        acc0[mt] = mfma32(wf, f3a[ks], acc0[mt]);
        acc1[mt] = mfma32(wf, f3b[ks], acc1[mt]);
      }
      __builtin_amdgcn_s_setprio(0);
    }
#pragma unroll
    for (int mt = 0; mt < 4; ++mt) {
      bf16x8 wf = *(const bf16x8*)(shB + ((36 + mt * 9 + 8) << 9) + l * 8);
      acc0[mt] = mfma32(wf, cf.v, acc0[mt]);
      acc1[mt] = mfma32(wf, cf.v, acc1[mt]);
    }

    asm volatile("s_waitcnt vmcnt(0)" ::: "memory");  // A(t+1) landed
    __builtin_amdgcn_s_barrier();                      // + WAR fence for B restage

    // ---- epilogue: ssq/dot, cs, tgt, latent accumulation (stores fly free)
    float ssq0 = 0.f, dot0 = 0.f, ssq1 = 0.f, dot1 = 0.f;
    const float* lg0b = langn + (size_t)tidn0 * 128;
    const float* lg1b = langn + (size_t)tidn1 * 128;
#pragma unroll
    for (int mt = 0; mt < 4; ++mt)
#pragma unroll
      for (int q = 0; q < 4; ++q) {
        int c0 = mt * 32 + q * 8 + 4 * hi;
        float4 lg0 = *(const float4*)(lg0b + c0);
        float4 lg1 = *(const float4*)(lg1b + c0);
        float a0 = acc0[mt][4 * q + 0], a1 = acc0[mt][4 * q + 1];
        float a2 = acc0[mt][4 * q + 2], a3 = acc0[mt][4 * q + 3];
        ssq0 += a0 * a0 + a1 * a1 + a2 * a2 + a3 * a3;
        dot0 += a0 * lg0.x + a1 * lg0.y + a2 * lg0.z + a3 * lg0.w;
        float c1 = acc1[mt][4 * q + 0], c2 = acc1[mt][4 * q + 1];
        float c3 = acc1[mt][4 * q + 2], c4 = acc1[mt][4 * q + 3];
        ssq1 += c1 * c1 + c2 * c2 + c3 * c3 + c4 * c4;
        dot1 += c1 * lg1.x + c2 * lg1.y + c3 * lg1.z + c4 * lg1.w;
      }
    ssq0 += __shfl_xor(ssq0, 32); dot0 += __shfl_xor(dot0, 32);
    ssq1 += __shfl_xor(ssq1, 32); dot1 += __shfl_xor(dot1, 32);
    float inv0 = rsqrtf(ssq0), inv1 = rsqrtf(ssq1);
    if (l < 32) {
      cs_t[(size_t)row0 * NTASK + n] = dot0 * inv0;
      cs_t[(size_t)(row0 + 32) * NTASK + n] = dot1 * inv1;
    }
    // latent += softmax(prior)[row,n] * inv * q   (q = acc, unnormalized)
    float pwi0 = pp_t[(size_t)n * BTOT + row0] * inv0;
    float pwi1 = pp_t[(size_t)n * BTOT + row0 + 32] * inv1;
#pragma unroll
    for (int mt = 0; mt < 4; ++mt) {
      lat0[mt] += acc0[mt] * pwi0;
      lat1[mt] += acc1[mt] * pwi1;
    }
    // latent_target: unique writer (row's own task)
    if (tidn0 == n) {
#pragma unroll
      for (int mt = 0; mt < 4; ++mt)
#pragma unroll
        for (int q = 0; q < 4; ++q) {
          float4 qv = {acc0[mt][4 * q + 0] * inv0, acc0[mt][4 * q + 1] * inv0,
                       acc0[mt][4 * q + 2] * inv0, acc0[mt][4 * q + 3] * inv0};
          *(float4*)(out_tgt + (size_t)row0 * 128 + mt * 32 + q * 8 + 4 * hi) = qv;
        }
    }
    if (tidn1 == n) {
#pragma unroll
      for (int mt = 0; mt < 4; ++mt)
#pragma unroll
        for (int q = 0; q < 4; ++q) {
          float4 qv = {acc1[mt][4 * q + 0] * inv1, acc1[mt][4 * q + 1] * inv1,
                       acc1[mt][4 * q + 2] * inv1, acc1[mt][4 * q + 3] * inv1};
          *(float4*)(out_tgt + (size_t)(row0 + 32) * 128 + mt * 32 + q * 8 + 4 * hi) = qv;
        }
    }
  }

  // ---- write partial latent for this task group
  float* lp0 = lat_part + ((size_t)tg * BTOT + row0) * 128;
  float* lp1 = lat_part + ((size_t)tg * BTOT + row0 + 32) * 128;
#pragma unroll
  for (int mt = 0; mt < 4; ++mt)
#pragma unroll
    for (int q = 0; q < 4; ++q) {
      int c0 = mt * 32 + q * 8 + 4 * hi;
      float4 v0 = {lat0[mt][4 * q + 0], lat0[mt][4 * q + 1],
                   lat0[mt][4 * q + 2], lat0[mt][4 * q + 3]};
      float4 v1 = {lat1[mt][4 * q + 0], lat1[mt][4 * q + 1],
                   lat1[mt][4 * q + 2], lat1[mt][4 * q + 3]};
      *(float4*)(lp0 + c0) = v0;
      *(float4*)(lp1 + c0) = v1;
    }
}

// ---------------- pass 3: per-row combine (1 wave per row) ----------------

__global__ void __launch_bounds__(256)
pass3_kernel(const float* __restrict__ state, const float* __restrict__ cs_t,
             const float* __restrict__ lat_part,
             float* __restrict__ out_rep, float* __restrict__ out_ltp,
             float* __restrict__ out_lat) {
  int w = threadIdx.x >> 6, l = threadIdx.x & 63;
  size_t row = (size_t)blockIdx.x * 4 + w;

  // log_softmax(cos*10)
  float c = (l < NTASK) ? cs_t[row * NTASK + l] * 10.0f : -1e30f;
  float cm = c;
#pragma unroll
  for (int mm = 1; mm < 64; mm <<= 1) cm = fmaxf(cm, __shfl_xor(cm, mm));
  float ce = (l < NTASK) ? expf(c - cm) : 0.0f;
  float cs = ce;
#pragma unroll
  for (int mm = 1; mm < 64; mm <<= 1) cs += __shfl_xor(cs, mm);
  if (l < NTASK) out_ltp[row * NTASK + l] = c - cm - logf(cs);

  // latent = sum of 4 task-group partials; lane covers cols {2l, 2l+1}
  float2 lv = {0.f, 0.f};
#pragma unroll
  for (int g = 0; g < 4; ++g) {
    float2 p = *(const float2*)(lat_part + ((size_t)g * BTOT + row) * 128 + 2 * l);
    lv.x += p.x; lv.y += p.y;
  }
  *(float2*)(out_lat + row * 128 + 2 * l) = lv;
  *(float2*)(out_rep + row * 384 + 256 + 2 * l) = lv;

  // state passthrough
  float4 sv = *(const float4*)(state + row * 256 + l * 4);
  *(float4*)(out_rep + row * 384 + l * 4) = sv;
}

// ---------------- launch ----------------

extern "C" void kernel_launch(void* const* d_in, const int* in_sizes, int n_in,
                              void* d_out, int out_size, void* d_ws, size_t ws_size,
                              hipStream_t stream) {
  (void)in_sizes; (void)n_in; (void)out_size; (void)ws_size;
  const float* state = (const float*)d_in[0];
  const int* task_id = (const int*)d_in[1];
  const float* prior = (const float*)d_in[2];
  const float* W1 = (const float*)d_in[3];
  const float* b1 = (const float*)d_in[4];
  const float* W2 = (const float*)d_in[5];
  const float* b2 = (const float*)d_in[6];
  const float* W3 = (const float*)d_in[7];
  const float* b3 = (const float*)d_in[8];
  const float* lang = (const float*)d_in[9];

  char* ws = (char*)d_ws;
  bf16* wstream  = (bf16*)(ws + 0);           //  5,013,504 B (34 x 144KB)
  bf16* sf       = (bf16*)(ws + 5013504);     //  8,388,608 B
  float* langn   = (float*)(ws + 13402112);   //     17,408 B
  float* pp_t    = (float*)(ws + 13419520);   //  2,228,224 B [34][16384]
  float* cs_t    = (float*)(ws + 15647744);   //  2,228,224 B [16384][34]
  float* lat_part= (float*)(ws + 17875968);   // 33,554,432 B [4][16384][128]
                                              // total 51,430,400 B

  float* out = (float*)d_out;
  float* out_rep = out;                 // [B,384]
  float* out_ltp = out + 6291456;       // [B,34]
  float* out_tgt = out + 6848512;       // [B,128]
  float* out_lat = out + 8945664;       // [B,128]

  prep_all<<<3238, 256, 0, stream>>>(W1, W2, W3, b1, b2, b3, state, wstream, sf);
  prep_langn<<<NTASK, 128, 0, stream>>>(lang, langn);
  prep_pprior<<<4096, 256, 0, stream>>>(prior, pp_t);
  pass1_kernel<<<256, 256, 0, stream>>>(task_id, wstream, sf, langn, pp_t,
                                        cs_t, lat_part, out_tgt);
  pass3_kernel<<<4096, 256, 0, stream>>>(state, cs_t, lat_part,
                                         out_rep, out_ltp, out_lat);
}